// Round 3
// baseline (1469.264 us; speedup 1.0000x reference)
//
#include <hip/hip_runtime.h>

// PerturbationModel: scores = counts @ log_mix^T (+ log comm bias), LSE over K, grand sum.
// G=3 S=10 N=5000 K=20 O=1000. counts 600 MB fp32 -> memory-bound, floor ~95 us.
//
// History:
//  R1: (512,4) + acc[4][20] spilled (launch_bounds arg2 is min-BLOCKS/CU here: cap 64).
//  R2: K-split + prefetch, (512,4) -> cap 64, spilled everything (988 MB scratch writes).
//  R3: same with (512,2) -> cap 128: VGPR pinned at 128, WRITE_SIZE 416 MB = acc[2 halves][10]
//      spilled once per granule. Natural demand (acc 40 + cur/next 32 + addr + L-pipe) > 128.
//  R4 (this): GRAN_ROWS 4 -> 2. acc[2][10]=20 regs + DEPTH-2 prefetch (cur/next/next2 = 24)
//      + addressing ~= 75-90 natural VGPR, fits the 128 cap with slack -> zero scratch.
//      Traffic/VALU ratios unchanged (bytes/FMA fixed); in-flight 2 KB/wave x 16 waves/CU
//      = 32 KB >> ~9 KB Little's-law need -> HBM-bound. Predict kernel ~110-170 us,
//      FETCH ~0.67 GB, WRITE ~0.

#define EPSF 1e-6f
constexpr int Gc = 3, Sc = 10, Nc = 5000, Kc = 20, Oc = 1000;
constexpr int ROWS_PER_G = Sc * Nc;                  // 50000
constexpr int GRAN_ROWS  = 2;                        // rows per wave-granule (shared by both lane halves)
constexpr int GRANS_PER_G = ROWS_PER_G / GRAN_ROWS;  // 25000 (exact)
constexpr int KH = Kc / 2;                           // 10 k's per lane-half
constexpr int LM_ELEMS = Kc * Oc;                    // 20000
constexpr int LM_ALLOC = LM_ELEMS + 32;              // guard pad for tail-lane float4 reads

// 32-lane-group sum via DPP (VALU pipe only). Result valid in lanes 31 and 63.
__device__ __forceinline__ float red32(float v) {
  v += __int_as_float(__builtin_amdgcn_update_dpp(0, __float_as_int(v), 0x111, 0xF, 0xF, true)); // row_shr:1
  v += __int_as_float(__builtin_amdgcn_update_dpp(0, __float_as_int(v), 0x112, 0xF, 0xF, true)); // row_shr:2
  v += __int_as_float(__builtin_amdgcn_update_dpp(0, __float_as_int(v), 0x114, 0xF, 0xF, true)); // row_shr:4
  v += __int_as_float(__builtin_amdgcn_update_dpp(0, __float_as_int(v), 0x118, 0xF, 0xF, true)); // row_shr:8
  v += __int_as_float(__builtin_amdgcn_update_dpp(0, __float_as_int(v), 0x142, 0xF, 0xF, true)); // row_bcast:15
  return v;
}

__global__ __launch_bounds__(512, 2) void perturb_kernel(
    const float* __restrict__ counts, const float* __restrict__ otu,
    const float* __restrict__ comm,   const float* __restrict__ cw,
    const float* __restrict__ cc,     const float* __restrict__ gamma_p,
    float* __restrict__ out) {
  // LDS: 80128 + 800 = 80928 B -> exactly 2 blocks/CU (2 x 80928 <= 163840)
  __shared__ float s_lm[LM_ALLOC];     // [k][o] log(mix+eps) for this block's g
  __shared__ float s_bias[Sc * Kc];    // [s][k] log(comm+eps) for this g

  const int tid  = threadIdx.x;
  const int bid  = blockIdx.x;
  const int g    = bid % Gc;
  const int bg   = bid / Gc;
  const int blocksg = (gridDim.x + (Gc - 1) - g) / Gc;

  const float cwg = cw[g];
  const float gam = gamma_p[0];

  // ---- stage log_mix + bias into LDS ----
  for (int idx = tid; idx < LM_ALLOC; idx += blockDim.x) {
    float v = 0.f;
    if (idx < LM_ELEMS) {
      int o = idx % Oc;                 // idx = k*1000 + o, otu is [K][O] so otu[idx]
      float mix = otu[idx] * (1.f - cwg) + cwg * cc[g * Oc + o];
      v = __logf(mix + EPSF);
    }
    s_lm[idx] = v;
  }
  for (int idx = tid; idx < Sc * Kc; idx += blockDim.x) {
    int s = idx / Kc, k = idx - s * Kc;
    s_bias[idx] = __logf(comm[(k * Gc + g) * Sc + s] + EPSF);
  }
  __syncthreads();

  const int wave = tid >> 6;
  const int lane = tid & 63;
  const int rl   = lane >> 5;          // which k-half this lane computes
  const int osub = lane & 31;          // o-column group within 128-o chunk
  const int k0   = rl * KH;            // 0 or 10
  const int oc0  = osub << 2;

  const int waveg  = bg * 8 + wave;    // wave index among this g's waves
  const int nwaveg = blocksg * 8;

  float lsum = 0.f;                    // per-lane LSE accumulator (valid in lane 31, rl==0)

  for (int gr = waveg; gr < GRANS_PER_G; gr += nwaveg) {
    const int row0 = gr * GRAN_ROWS;   // g-local first row; both halves cover rows row0, row0+1
    const float* base = counts + (size_t)(g * ROWS_PER_G + row0) * Oc;

    float acc[GRAN_ROWS][KH];
#pragma unroll
    for (int r = 0; r < GRAN_ROWS; ++r)
#pragma unroll
      for (int kk = 0; kk < KH; ++kk) acc[r][kk] = 0.f;

    // depth-2 prefetch pipeline over 8 chunks of 128 o's (chunk 7 = tail, 26 active lanes)
    float4 c0 = *(const float4*)(base + 0 * Oc + oc0);          // chunk 0
    float4 c1 = *(const float4*)(base + 1 * Oc + oc0);
    float4 n0 = *(const float4*)(base + 0 * Oc + 128 + oc0);    // chunk 1
    float4 n1 = *(const float4*)(base + 1 * Oc + 128 + oc0);

#pragma unroll
    for (int j = 0; j < 8; ++j) {
      float4 p0 = {0,0,0,0}, p1 = {0,0,0,0};
      if (j < 6) {                      // prefetch chunk j+2 (chunk 7 masked to 26 lanes)
        const int obn = (j + 2) * 128 + oc0;
        if (j < 5 || osub < 26) {
          p0 = *(const float4*)(base + 0 * Oc + obn);
          p1 = *(const float4*)(base + 1 * Oc + obn);
        }
      }
      const int ob = j * 128 + oc0;
      const float* lp = &s_lm[k0 * Oc + ob];
      // chunk 7: masked lanes hold c=={0}; s_lm reads past o=1000 hit next-k row / guard pad,
      // multiplied by 0 -> harmless (pad is 0, rows are finite).
#pragma unroll
      for (int kk = 0; kk < KH; ++kk) {
        float4 L = *(const float4*)(lp + kk * Oc);
        acc[0][kk] += c0.x * L.x + c0.y * L.y + c0.z * L.z + c0.w * L.w;
        acc[1][kk] += c1.x * L.x + c1.y * L.y + c1.z * L.z + c1.w * L.w;
      }
      c0 = n0; c1 = n1; n0 = p0; n1 = p1;
    }

    // reduce each acc over the 32 o-lanes (DPP, VALU pipe). lanes 31/63 hold half-sums.
#pragma unroll
    for (int r = 0; r < GRAN_ROWS; ++r)
#pragma unroll
      for (int kk = 0; kk < KH; ++kk) acc[r][kk] = red32(acc[r][kk]);

    if ((lane & 31) == 31) {           // lanes 31 (k=0..9) and 63 (k=10..19) active
#pragma unroll
      for (int r = 0; r < GRAN_ROWS; ++r) {
        const int s = (row0 + r) / Nc;
        const float* bp = &s_bias[s * Kc + k0];
        float m = -3.4e38f;
#pragma unroll
        for (int kk = 0; kk < KH; ++kk) {
          acc[r][kk] += bp[kk];        // reuse acc in place
          m = fmaxf(m, acc[r][kk]);
        }
        // combine the two k-halves: lane31 <-> lane63
        const float mo = __shfl_xor(m, 32);
        const float mm = fmaxf(m, mo);
        float ssum = 0.f;
#pragma unroll
        for (int kk = 0; kk < KH; ++kk) ssum += __expf(gam * (acc[r][kk] - mm));
        const float so = __shfl_xor(ssum, 32);
        if (rl == 0) lsum += mm + __logf(ssum + so);
      }
    }
  }

  if (lane == 31) atomicAdd(out, lsum);
}

extern "C" void kernel_launch(void* const* d_in, const int* in_sizes, int n_in,
                              void* d_out, int out_size, void* d_ws, size_t ws_size,
                              hipStream_t stream) {
  const float* counts = (const float*)d_in[0];
  const float* otu    = (const float*)d_in[1];
  const float* comm   = (const float*)d_in[2];
  const float* cw     = (const float*)d_in[3];
  const float* cc     = (const float*)d_in[4];
  const float* gam    = (const float*)d_in[5];
  float* out = (float*)d_out;

  hipMemsetAsync(out, 0, sizeof(float), stream);
  hipLaunchKernelGGL(perturb_kernel, dim3(512), dim3(512), 0, stream,
                     counts, otu, comm, cw, cc, gam, out);
}

// Round 4
// 841.045 us; speedup vs baseline: 1.7469x; 1.7469x over previous
//
#include <hip/hip_runtime.h>

// PerturbationModel: scores = counts @ log_mix^T (+ log comm bias), LSE over K, grand sum.
// G=3 S=10 N=5000 K=20 O=1000. counts 600 MB fp32 -> memory-bound, floor ~95 us.
//
// History:
//  R1: (512,4) + acc[4][20] spilled (launch_bounds arg2 is min-BLOCKS/CU here: cap 64).
//  R2: K-split + prefetch, (512,4) -> cap 64, spilled everything (988 MB scratch writes).
//  R3: (512,2) cap 128: spill = acc[4][10] once/granule (416 MB). R4: acc[2][10], spill
//      = acc[2][10] once/granule (413 MB) -- shrinking acc didn't help. Diagnosis: the
//      FULLY UNROLLED 8-chunk loop lets the scheduler hoist/cluster global loads (up to
//      64 VGPRs of count data live) + pipelined L reads -> peak pressure >> 128, and the
//      allocator evicts the longest-lived values: acc. Both rounds spilled exactly acc.
//  R5 (this): chunk loop kept ROLLED (#pragma unroll 1). Rotating c/n buffers become
//      fixed phi regs: acc(20)+c(8)+n(8)+L-pipe(~16)+addr(~10) ~= 75 natural VGPR.
//      Depth-1 prefetch via rolled-loop vmcnt (n-loads issued at loop top stay in flight
//      through the 10x ds_read_b128 + 80 fma compute phase). 2 KB/wave x 16 waves/CU
//      in flight >> ~9 KB/CU Little's-law need -> HBM-bound.
//      Predict: VGPR <128 (not pinned), WRITE ~0, FETCH ~0.66 GB, kernel ~110-160 us.

#define EPSF 1e-6f
constexpr int Gc = 3, Sc = 10, Nc = 5000, Kc = 20, Oc = 1000;
constexpr int ROWS_PER_G = Sc * Nc;                  // 50000
constexpr int GRAN_ROWS  = 2;                        // rows per wave-granule (shared by both lane halves)
constexpr int GRANS_PER_G = ROWS_PER_G / GRAN_ROWS;  // 25000 (exact)
constexpr int KH = Kc / 2;                           // 10 k's per lane-half
constexpr int LM_ELEMS = Kc * Oc;                    // 20000
constexpr int LM_ALLOC = LM_ELEMS + 32;              // guard pad for tail-lane float4 reads

// 32-lane-group sum via DPP (VALU pipe only). Result valid in lanes 31 and 63.
__device__ __forceinline__ float red32(float v) {
  v += __int_as_float(__builtin_amdgcn_update_dpp(0, __float_as_int(v), 0x111, 0xF, 0xF, true)); // row_shr:1
  v += __int_as_float(__builtin_amdgcn_update_dpp(0, __float_as_int(v), 0x112, 0xF, 0xF, true)); // row_shr:2
  v += __int_as_float(__builtin_amdgcn_update_dpp(0, __float_as_int(v), 0x114, 0xF, 0xF, true)); // row_shr:4
  v += __int_as_float(__builtin_amdgcn_update_dpp(0, __float_as_int(v), 0x118, 0xF, 0xF, true)); // row_shr:8
  v += __int_as_float(__builtin_amdgcn_update_dpp(0, __float_as_int(v), 0x142, 0xF, 0xF, true)); // row_bcast:15
  return v;
}

__global__ __launch_bounds__(512, 2) void perturb_kernel(
    const float* __restrict__ counts, const float* __restrict__ otu,
    const float* __restrict__ comm,   const float* __restrict__ cw,
    const float* __restrict__ cc,     const float* __restrict__ gamma_p,
    float* __restrict__ out) {
  // LDS: 80128 + 800 = 80928 B -> exactly 2 blocks/CU (2 x 80928 <= 163840)
  __shared__ float s_lm[LM_ALLOC];     // [k][o] log(mix+eps) for this block's g
  __shared__ float s_bias[Sc * Kc];    // [s][k] log(comm+eps) for this g

  const int tid  = threadIdx.x;
  const int bid  = blockIdx.x;
  const int g    = bid % Gc;
  const int bg   = bid / Gc;
  const int blocksg = (gridDim.x + (Gc - 1) - g) / Gc;

  const float cwg = cw[g];
  const float gam = gamma_p[0];

  // ---- stage log_mix + bias into LDS ----
  for (int idx = tid; idx < LM_ALLOC; idx += blockDim.x) {
    float v = 0.f;
    if (idx < LM_ELEMS) {
      int o = idx % Oc;                 // idx = k*1000 + o, otu is [K][O] so otu[idx]
      float mix = otu[idx] * (1.f - cwg) + cwg * cc[g * Oc + o];
      v = __logf(mix + EPSF);
    }
    s_lm[idx] = v;
  }
  for (int idx = tid; idx < Sc * Kc; idx += blockDim.x) {
    int s = idx / Kc, k = idx - s * Kc;
    s_bias[idx] = __logf(comm[(k * Gc + g) * Sc + s] + EPSF);
  }
  __syncthreads();

  const int wave = tid >> 6;
  const int lane = tid & 63;
  const int rl   = lane >> 5;          // which k-half this lane computes
  const int osub = lane & 31;          // o-column group within 128-o chunk
  const int k0   = rl * KH;            // 0 or 10
  const int oc0  = osub << 2;

  const int waveg  = bg * 8 + wave;    // wave index among this g's waves
  const int nwaveg = blocksg * 8;

  float lsum = 0.f;                    // per-lane LSE accumulator (valid in lane 31, rl==0)

  for (int gr = waveg; gr < GRANS_PER_G; gr += nwaveg) {
    const int row0 = gr * GRAN_ROWS;   // g-local first row; both halves cover rows row0, row0+1
    const float* base = counts + (size_t)(g * ROWS_PER_G + row0) * Oc;

    float acc[GRAN_ROWS][KH];
#pragma unroll
    for (int r = 0; r < GRAN_ROWS; ++r)
#pragma unroll
      for (int kk = 0; kk < KH; ++kk) acc[r][kk] = 0.f;

    // chunk 0 loads (o in [0,128), fully in-range)
    float4 c0 = *(const float4*)(base + 0 * Oc + oc0);
    float4 c1 = *(const float4*)(base + 1 * Oc + oc0);

    // ROLLED loop over 8 chunks of 128 o's (chunk 7 = tail: 26 active float4 lanes).
    // Rolled => rotating c/n stay as fixed phi registers; n-loads issued at loop top
    // remain in flight (vmcnt) across the ds_read+fma phase below. Do NOT unroll.
#pragma unroll 1
    for (int j = 0; j < 8; ++j) {
      float4 n0 = {0,0,0,0}, n1 = {0,0,0,0};
      if (j < 7 && (j < 6 || osub < 26)) {   // prefetch chunk j+1 (chunk 7 masked)
        const int obn = (j + 1) * 128 + oc0;
        n0 = *(const float4*)(base + 0 * Oc + obn);
        n1 = *(const float4*)(base + 1 * Oc + obn);
      }
      const int ob = j * 128 + oc0;
      const float* lp = &s_lm[k0 * Oc + ob];
      // chunk 7: masked lanes hold c=={0}; s_lm reads past o=1000 hit next-k row / guard
      // pad, multiplied by 0 -> harmless (pad is 0, rows are finite).
#pragma unroll
      for (int kk = 0; kk < KH; ++kk) {
        float4 L = *(const float4*)(lp + kk * Oc);
        acc[0][kk] += c0.x * L.x + c0.y * L.y + c0.z * L.z + c0.w * L.w;
        acc[1][kk] += c1.x * L.x + c1.y * L.y + c1.z * L.z + c1.w * L.w;
      }
      c0 = n0; c1 = n1;
    }

    // reduce each acc over the 32 o-lanes (DPP, VALU pipe). lanes 31/63 hold half-sums.
#pragma unroll
    for (int r = 0; r < GRAN_ROWS; ++r)
#pragma unroll
      for (int kk = 0; kk < KH; ++kk) acc[r][kk] = red32(acc[r][kk]);

    if ((lane & 31) == 31) {           // lanes 31 (k=0..9) and 63 (k=10..19) active
#pragma unroll
      for (int r = 0; r < GRAN_ROWS; ++r) {
        const int s = (row0 + r) / Nc;
        const float* bp = &s_bias[s * Kc + k0];
        float m = -3.4e38f;
#pragma unroll
        for (int kk = 0; kk < KH; ++kk) {
          acc[r][kk] += bp[kk];        // reuse acc in place
          m = fmaxf(m, acc[r][kk]);
        }
        // combine the two k-halves: lane31 <-> lane63
        const float mo = __shfl_xor(m, 32);
        const float mm = fmaxf(m, mo);
        float ssum = 0.f;
#pragma unroll
        for (int kk = 0; kk < KH; ++kk) ssum += __expf(gam * (acc[r][kk] - mm));
        const float so = __shfl_xor(ssum, 32);
        if (rl == 0) lsum += mm + __logf(ssum + so);
      }
    }
  }

  if (lane == 31) atomicAdd(out, lsum);
}

extern "C" void kernel_launch(void* const* d_in, const int* in_sizes, int n_in,
                              void* d_out, int out_size, void* d_ws, size_t ws_size,
                              hipStream_t stream) {
  const float* counts = (const float*)d_in[0];
  const float* otu    = (const float*)d_in[1];
  const float* comm   = (const float*)d_in[2];
  const float* cw     = (const float*)d_in[3];
  const float* cc     = (const float*)d_in[4];
  const float* gam    = (const float*)d_in[5];
  float* out = (float*)d_out;

  hipMemsetAsync(out, 0, sizeof(float), stream);
  hipLaunchKernelGGL(perturb_kernel, dim3(512), dim3(512), 0, stream,
                     counts, otu, comm, cw, cc, gam, out);
}